// Round 1
// baseline (1722.569 us; speedup 1.0000x reference)
//
#include <hip/hip_runtime.h>
#include <hip/hip_bf16.h>
#include <math.h>

#define EPSF 1e-6f

// Problem constants (fixed by setup_inputs): B=8, N=4096, D=512, H=8, d=64
constexpr int Bc = 8;
constexpr int Nc = 4096;
constexpr int Dc = 512;
constexpr int Hc = 8;
constexpr int QKVC = 3 * Dc;  // 1536

// ---------------------------------------------------------------------------
// Kernel 1 & 4: C[M,Ncols] = A[M,K] @ Bm[Ncols,K]^T  (row-major, both K-contig)
// 64x64 tile, BK=16, 256 threads, 4x4 microtile.
// ELU_COLS>0: apply elu(x)+1+eps to columns < ELU_COLS (q and k of qkv).
// BIAS: add bias[col].
// ---------------------------------------------------------------------------
template <int ELU_COLS, bool BIAS>
__global__ __launch_bounds__(256) void sgemm_bt(
    const float* __restrict__ A, int lda,
    const float* __restrict__ Bm, int ldb,
    float* __restrict__ C, int ldc,
    int K, const float* __restrict__ bias)
{
    __shared__ float As[16][65];
    __shared__ float Bs[16][65];

    const int t  = threadIdx.x;
    const int bm = blockIdx.x * 64;
    const int bn = blockIdx.y * 64;
    const int lr = t >> 2;          // 0..63 load row
    const int lc = (t & 3) << 2;    // 0,4,8,12 float4 slot within BK=16
    const int tm = (t >> 4) << 2;   // 0..60 microtile row base
    const int tn = (t & 15) << 2;   // 0..60 microtile col base

    const float* Ap = A + (size_t)(bm + lr) * lda + lc;
    const float* Bp = Bm + (size_t)(bn + lr) * ldb + lc;

    float acc[4][4] = {};

    for (int k0 = 0; k0 < K; k0 += 16) {
        float4 av = *reinterpret_cast<const float4*>(Ap + k0);
        float4 bv = *reinterpret_cast<const float4*>(Bp + k0);
        As[lc + 0][lr] = av.x; As[lc + 1][lr] = av.y;
        As[lc + 2][lr] = av.z; As[lc + 3][lr] = av.w;
        Bs[lc + 0][lr] = bv.x; Bs[lc + 1][lr] = bv.y;
        Bs[lc + 2][lr] = bv.z; Bs[lc + 3][lr] = bv.w;
        __syncthreads();
#pragma unroll
        for (int k = 0; k < 16; ++k) {
            const float a0 = As[k][tm + 0], a1 = As[k][tm + 1];
            const float a2 = As[k][tm + 2], a3 = As[k][tm + 3];
            const float b0 = Bs[k][tn + 0], b1 = Bs[k][tn + 1];
            const float b2 = Bs[k][tn + 2], b3 = Bs[k][tn + 3];
            acc[0][0] += a0 * b0; acc[0][1] += a0 * b1; acc[0][2] += a0 * b2; acc[0][3] += a0 * b3;
            acc[1][0] += a1 * b0; acc[1][1] += a1 * b1; acc[1][2] += a1 * b2; acc[1][3] += a1 * b3;
            acc[2][0] += a2 * b0; acc[2][1] += a2 * b1; acc[2][2] += a2 * b2; acc[2][3] += a2 * b3;
            acc[3][0] += a3 * b0; acc[3][1] += a3 * b1; acc[3][2] += a3 * b2; acc[3][3] += a3 * b3;
        }
        __syncthreads();
    }

#pragma unroll
    for (int i = 0; i < 4; ++i) {
#pragma unroll
        for (int j = 0; j < 4; ++j) {
            const int col = bn + tn + j;
            float v = acc[i][j];
            if (ELU_COLS > 0 && col < ELU_COLS) {
                // elu(v) + 1 + eps : v>0 -> v+1+eps ; else exp(v)-1+1+eps = exp(v)+eps
                v = (v > 0.f) ? (v + 1.0f + EPSF) : (expf(v) + EPSF);
            }
            if (BIAS) v += bias[col];
            C[(size_t)(bm + tm + i) * ldc + col] = v;
        }
    }
}

// ---------------------------------------------------------------------------
// Kernel 2: per (b,h): kv[d][e] = sum_n k[n,d]*v[n,e]; ksum[d] = sum_n k[n,d]
// One block per (b,h) over full N -> no atomics, deterministic.
// ---------------------------------------------------------------------------
__global__ __launch_bounds__(256) void kv_summary(
    const float* __restrict__ qkv, float* __restrict__ kvbuf,
    float* __restrict__ ksum)
{
    const int bh = blockIdx.x;     // 0..63
    const int b = bh >> 3, h = bh & 7;

    __shared__ float kt[64][65];
    __shared__ float vt[64][65];
    __shared__ float ksp[4][64];

    const int t  = threadIdx.x;
    const int lr = t >> 2;          // 0..63 load row
    const int lc = (t & 3) << 4;    // 0,16,32,48
    const int e  = t & 63;
    const int dg = t >> 6;          // 0..3 (wave id)

    float acc[16] = {};
    float ks = 0.f;

    const size_t base = ((size_t)b * Nc) * QKVC + (size_t)h * 64;

    for (int n0 = 0; n0 < Nc; n0 += 64) {
        const float* kr = qkv + base + (size_t)(n0 + lr) * QKVC + Dc + lc;
        const float* vr = kr + Dc;
#pragma unroll
        for (int i = 0; i < 4; ++i) {
            float4 kq = *reinterpret_cast<const float4*>(kr + i * 4);
            float4 vq = *reinterpret_cast<const float4*>(vr + i * 4);
            kt[lr][lc + i * 4 + 0] = kq.x; kt[lr][lc + i * 4 + 1] = kq.y;
            kt[lr][lc + i * 4 + 2] = kq.z; kt[lr][lc + i * 4 + 3] = kq.w;
            vt[lr][lc + i * 4 + 0] = vq.x; vt[lr][lc + i * 4 + 1] = vq.y;
            vt[lr][lc + i * 4 + 2] = vq.z; vt[lr][lc + i * 4 + 3] = vq.w;
        }
        __syncthreads();
#pragma unroll 4
        for (int nn = 0; nn < 64; ++nn) {
            const float vv = vt[nn][e];   // stride-1 across lanes
#pragma unroll
            for (int i = 0; i < 16; ++i)
                acc[i] += kt[nn][dg * 16 + i] * vv;  // wave-uniform broadcast
        }
#pragma unroll
        for (int nn = 0; nn < 16; ++nn) ks += kt[dg * 16 + nn][e];
        __syncthreads();
    }

    ksp[dg][e] = ks;
    __syncthreads();

    float* kvp = kvbuf + (size_t)bh * 4096;
#pragma unroll
    for (int i = 0; i < 16; ++i) kvp[(dg * 16 + i) * 64 + e] = acc[i];
    if (t < 64) ksum[bh * 64 + t] = ksp[0][t] + ksp[1][t] + ksp[2][t] + ksp[3][t];
}

// ---------------------------------------------------------------------------
// Kernel 3: out[n, h*64+e] = (sum_d q[n,d]*kv[d][e]) / (q.ksum + eps)
// Written IN PLACE over the q columns of the qkv buffer.
// One thread per (b,h,n) row.
// ---------------------------------------------------------------------------
__global__ __launch_bounds__(256) void attn_out(
    float* __restrict__ qkv, const float* __restrict__ kvbuf,
    const float* __restrict__ ksum)
{
    const int bh = blockIdx.x;
    const int b = bh >> 3, h = bh & 7;
    const int t = threadIdx.x;
    const int n = blockIdx.y * 256 + t;

    __shared__ float kvs[64][65];
    __shared__ float kss[64];

    {
        const int d0 = t >> 2;
        const int c0 = (t & 3) << 4;
        const float* src = kvbuf + (size_t)bh * 4096 + d0 * 64 + c0;
#pragma unroll
        for (int i = 0; i < 4; ++i) {
            float4 v = *reinterpret_cast<const float4*>(src + i * 4);
            kvs[d0][c0 + i * 4 + 0] = v.x; kvs[d0][c0 + i * 4 + 1] = v.y;
            kvs[d0][c0 + i * 4 + 2] = v.z; kvs[d0][c0 + i * 4 + 3] = v.w;
        }
        if (t < 64) kss[t] = ksum[bh * 64 + t];
    }
    __syncthreads();

    float* row = qkv + ((size_t)b * Nc + n) * QKVC + h * 64;

    float q[64];
#pragma unroll
    for (int i = 0; i < 16; ++i) {
        float4 v = *reinterpret_cast<const float4*>(row + i * 4);
        q[i * 4 + 0] = v.x; q[i * 4 + 1] = v.y;
        q[i * 4 + 2] = v.z; q[i * 4 + 3] = v.w;
    }

    float denom = EPSF;
#pragma unroll
    for (int d = 0; d < 64; ++d) denom += q[d] * kss[d];
    const float inv = 1.0f / denom;

    for (int e4 = 0; e4 < 16; ++e4) {
        float o0 = 0.f, o1 = 0.f, o2 = 0.f, o3 = 0.f;
#pragma unroll
        for (int d = 0; d < 64; ++d) {
            const float qd = q[d];
            o0 += qd * kvs[d][e4 * 4 + 0];
            o1 += qd * kvs[d][e4 * 4 + 1];
            o2 += qd * kvs[d][e4 * 4 + 2];
            o3 += qd * kvs[d][e4 * 4 + 3];
        }
        float4 ov = make_float4(o0 * inv, o1 * inv, o2 * inv, o3 * inv);
        *reinterpret_cast<float4*>(row + e4 * 4) = ov;  // q already in regs: safe
    }
}

// ---------------------------------------------------------------------------
extern "C" void kernel_launch(void* const* d_in, const int* in_sizes, int n_in,
                              void* d_out, int out_size, void* d_ws, size_t ws_size,
                              hipStream_t stream)
{
    const float* x      = (const float*)d_in[0];  // [8,4096,512]
    const float* w_qkv  = (const float*)d_in[1];  // [1536,512]
    const float* w_proj = (const float*)d_in[2];  // [512,512]
    const float* b_proj = (const float*)d_in[3];  // [512]
    float* out = (float*)d_out;                   // [8,4096,512]

    char* ws = (char*)d_ws;
    float* qkv   = (float*)ws;                                    // 32768x1536 f32 = 192 MiB
    float* kvbuf = (float*)(ws + (size_t)32768 * 1536 * sizeof(float)); // 64x64x64 f32
    float* ksumb = kvbuf + 64 * 4096;                             // 64x64 f32

    const dim3 blk(256);

    // 1) qkv = x @ w_qkv^T with fused elu+1+eps on q,k columns (<1024)
    sgemm_bt<1024, false><<<dim3(32768 / 64, QKVC / 64), blk, 0, stream>>>(
        x, Dc, w_qkv, Dc, qkv, QKVC, Dc, nullptr);

    // 2) per-(b,h) kv summary + ksum
    kv_summary<<<dim3(Bc * Hc), blk, 0, stream>>>(qkv, kvbuf, ksumb);

    // 3) attention output, in place over q columns
    attn_out<<<dim3(Bc * Hc, Nc / 256), blk, 0, stream>>>(qkv, kvbuf, ksumb);

    // 4) out = attn @ w_proj^T + b_proj  (attn lives in qkv cols 0..511, lda=1536)
    sgemm_bt<0, true><<<dim3(32768 / 64, Dc / 64), blk, 0, stream>>>(
        qkv, QKVC, w_proj, Dc, out, Dc, Dc, b_proj);
}

// Round 2
// 216.467 us; speedup vs baseline: 7.9577x; 7.9577x over previous
//
#include <hip/hip_runtime.h>
#include <hip/hip_bf16.h>
#include <math.h>

#define EPSF 1e-6f

constexpr int Bc = 8;
constexpr int Nc = 4096;
constexpr int Dc = 512;
constexpr int QKVC = 3 * Dc;  // 1536

typedef __attribute__((ext_vector_type(8))) short short8v;
typedef __attribute__((ext_vector_type(8))) unsigned short ushort8v;
typedef __attribute__((ext_vector_type(4))) float float4v;

__device__ __forceinline__ unsigned short f2bf(float f) {
    union { float f; unsigned int u; } v; v.f = f;
    unsigned int u = v.u;
    return (unsigned short)((u + 0x7fffu + ((u >> 16) & 1u)) >> 16);
}
__device__ __forceinline__ float bf2f(unsigned short h) {
    union { unsigned int u; float f; } v; v.u = ((unsigned int)h) << 16;
    return v.f;
}

typedef __attribute__((address_space(1))) const void gvoid_t;
typedef __attribute__((address_space(3))) void lvoid_t;
__device__ __forceinline__ void llds16(const void* g, void* l) {
    __builtin_amdgcn_global_load_lds((gvoid_t*)g, (lvoid_t*)l, 16, 0, 0);
}

// ---------------------------------------------------------------------------
// f32 -> bf16 conversion, 8 elems/thread
// ---------------------------------------------------------------------------
__global__ __launch_bounds__(256) void cvt_f32_bf16(
    const float* __restrict__ in, unsigned short* __restrict__ out, int n8)
{
    int i = blockIdx.x * 256 + threadIdx.x;
    if (i >= n8) return;
    float4 a = reinterpret_cast<const float4*>(in)[2 * i];
    float4 b = reinterpret_cast<const float4*>(in)[2 * i + 1];
    ushort8v o;
    o[0] = f2bf(a.x); o[1] = f2bf(a.y); o[2] = f2bf(a.z); o[3] = f2bf(a.w);
    o[4] = f2bf(b.x); o[5] = f2bf(b.y); o[6] = f2bf(b.z); o[7] = f2bf(b.w);
    reinterpret_cast<ushort8v*>(out)[i] = o;
}

// ---------------------------------------------------------------------------
// bf16 MFMA GEMM: C[M,N] = A[M,K] @ Bm[N,K]^T   (both row-major, K-contig)
// 128x128 tile, BK=32, 256 threads (4 waves, 2x2), 4x4 frags of 16x16x32/wave.
// ELU_COLS>0: elu(v)+1+eps on cols < ELU_COLS. BIAS: +bias[col].
// OUT_BF16: store bf16, else f32.
// ---------------------------------------------------------------------------
template <int ELU_COLS, bool BIAS, bool OUT_BF16>
__global__ __launch_bounds__(256) void gemm_bf16(
    const unsigned short* __restrict__ A, int lda,
    const unsigned short* __restrict__ Bm, int ldb,
    void* __restrict__ Cout, int ldc, int K,
    const float* __restrict__ bias)
{
    __shared__ unsigned short lA[128 * 32];
    __shared__ unsigned short lB[128 * 32];

    const int t    = threadIdx.x;
    const int bm   = blockIdx.x * 128;
    const int bn   = blockIdx.y * 128;
    const int w    = t >> 6, lane = t & 63;
    const int ln   = lane & 15, g = lane >> 4;
    const int wr   = (w >> 1) * 64, wc = (w & 1) * 64;

    // staging: chunk c (0..511) -> LDS ushort off c*8; row=c>>2, kslot=(c&3)*8
    const int r0  = t >> 2;
    const int ks0 = (t & 3) * 8;
    const unsigned short* Ap0 = A + (size_t)(bm + r0) * lda + ks0;
    const unsigned short* Ap1 = A + (size_t)(bm + r0 + 64) * lda + ks0;
    const unsigned short* Bp0 = Bm + (size_t)(bn + r0) * ldb + ks0;
    const unsigned short* Bp1 = Bm + (size_t)(bn + r0 + 64) * ldb + ks0;
    unsigned short* lA0 = lA + (size_t)t * 8;
    unsigned short* lA1 = lA + (size_t)(t + 256) * 8;
    unsigned short* lB0 = lB + (size_t)t * 8;
    unsigned short* lB1 = lB + (size_t)(t + 256) * 8;

    float4v acc[4][4];
#pragma unroll
    for (int i = 0; i < 4; ++i)
#pragma unroll
        for (int j = 0; j < 4; ++j) acc[i][j] = {0.f, 0.f, 0.f, 0.f};

    for (int k0 = 0; k0 < K; k0 += 32) {
        llds16(Ap0 + k0, lA0);
        llds16(Ap1 + k0, lA1);
        llds16(Bp0 + k0, lB0);
        llds16(Bp1 + k0, lB1);
        __syncthreads();

        short8v a[4], b[4];
#pragma unroll
        for (int i = 0; i < 4; ++i)
            a[i] = *reinterpret_cast<const short8v*>(lA + (wr + i * 16 + ln) * 32 + g * 8);
#pragma unroll
        for (int j = 0; j < 4; ++j)
            b[j] = *reinterpret_cast<const short8v*>(lB + (wc + j * 16 + ln) * 32 + g * 8);
#pragma unroll
        for (int i = 0; i < 4; ++i)
#pragma unroll
            for (int j = 0; j < 4; ++j)
                acc[i][j] = __builtin_amdgcn_mfma_f32_16x16x32_bf16(a[i], b[j], acc[i][j], 0, 0, 0);
        __syncthreads();
    }

    // epilogue: D[row=(g*4+r), col=ln] per frag (m89-verified layout)
#pragma unroll
    for (int i = 0; i < 4; ++i) {
        const int Rb = bm + wr + i * 16 + g * 4;
#pragma unroll
        for (int j = 0; j < 4; ++j) {
            const int Cc = bn + wc + j * 16 + ln;
            const bool do_elu = (ELU_COLS > 0) && (Cc < ELU_COLS);
            float bv = BIAS ? bias[Cc] : 0.f;
#pragma unroll
            for (int r = 0; r < 4; ++r) {
                float v = acc[i][j][r];
                if (do_elu) v = (v > 0.f) ? (v + 1.0f + EPSF) : (expf(v) + EPSF);
                if (BIAS) v += bv;
                if (OUT_BF16)
                    ((unsigned short*)Cout)[(size_t)(Rb + r) * ldc + Cc] = f2bf(v);
                else
                    ((float*)Cout)[(size_t)(Rb + r) * ldc + Cc] = v;
            }
        }
    }
}

// ---------------------------------------------------------------------------
// kv partials: per (bh, chunk of 512 rows): kvp[d][e] = sum k[n,d]*v[n,e],
// ksp[d] = sum k[n,d].  Deterministic (fixed order), reduced in kv_reduce.
// ---------------------------------------------------------------------------
__global__ __launch_bounds__(256) void kv_part(
    const unsigned short* __restrict__ qkv,
    float* __restrict__ kvp, float* __restrict__ ksp)
{
    const int bh = blockIdx.x, chunk = blockIdx.y;
    const int b = bh >> 3, h = bh & 7;

    __shared__ float kt[64][68];
    __shared__ float vt[64][68];
    __shared__ float ksl[4][64];

    const int t  = threadIdx.x;
    const int e  = t & 63, dg = t >> 6;
    const int rr = t >> 3, slot = t & 7;

    float acc[16] = {};
    float ks = 0.f;

    const size_t base = ((size_t)b * Nc + (size_t)chunk * 512) * QKVC + h * 64;

    for (int n0 = 0; n0 < 512; n0 += 64) {
#pragma unroll
        for (int half = 0; half < 2; ++half) {
            const int row = rr + half * 32;
            const unsigned short* kr = qkv + base + (size_t)(n0 + row) * QKVC + Dc + slot * 8;
            const unsigned short* vr = kr + Dc;
            ushort8v kq = *reinterpret_cast<const ushort8v*>(kr);
            ushort8v vq = *reinterpret_cast<const ushort8v*>(vr);
            float4 k0 = make_float4(bf2f(kq[0]), bf2f(kq[1]), bf2f(kq[2]), bf2f(kq[3]));
            float4 k1 = make_float4(bf2f(kq[4]), bf2f(kq[5]), bf2f(kq[6]), bf2f(kq[7]));
            float4 v0 = make_float4(bf2f(vq[0]), bf2f(vq[1]), bf2f(vq[2]), bf2f(vq[3]));
            float4 v1 = make_float4(bf2f(vq[4]), bf2f(vq[5]), bf2f(vq[6]), bf2f(vq[7]));
            *reinterpret_cast<float4*>(&kt[row][slot * 8])     = k0;
            *reinterpret_cast<float4*>(&kt[row][slot * 8 + 4]) = k1;
            *reinterpret_cast<float4*>(&vt[row][slot * 8])     = v0;
            *reinterpret_cast<float4*>(&vt[row][slot * 8 + 4]) = v1;
        }
        __syncthreads();
#pragma unroll 2
        for (int nn = 0; nn < 64; ++nn) {
            const float vv = vt[nn][e];
            const float4 q0 = *reinterpret_cast<const float4*>(&kt[nn][dg * 16]);
            const float4 q1 = *reinterpret_cast<const float4*>(&kt[nn][dg * 16 + 4]);
            const float4 q2 = *reinterpret_cast<const float4*>(&kt[nn][dg * 16 + 8]);
            const float4 q3 = *reinterpret_cast<const float4*>(&kt[nn][dg * 16 + 12]);
            acc[0]  += q0.x * vv; acc[1]  += q0.y * vv; acc[2]  += q0.z * vv; acc[3]  += q0.w * vv;
            acc[4]  += q1.x * vv; acc[5]  += q1.y * vv; acc[6]  += q1.z * vv; acc[7]  += q1.w * vv;
            acc[8]  += q2.x * vv; acc[9]  += q2.y * vv; acc[10] += q2.z * vv; acc[11] += q2.w * vv;
            acc[12] += q3.x * vv; acc[13] += q3.y * vv; acc[14] += q3.z * vv; acc[15] += q3.w * vv;
        }
#pragma unroll
        for (int nn = 0; nn < 16; ++nn) ks += kt[dg * 16 + nn][e];
        __syncthreads();
    }

    float* kvpp = kvp + ((size_t)bh * 8 + chunk) * 4096;
#pragma unroll
    for (int i = 0; i < 16; ++i) kvpp[(dg * 16 + i) * 64 + e] = acc[i];

    ksl[dg][e] = ks;
    __syncthreads();
    if (t < 64) ksp[((size_t)bh * 8 + chunk) * 64 + t] =
        ksl[0][t] + ksl[1][t] + ksl[2][t] + ksl[3][t];
}

// ---------------------------------------------------------------------------
// reduce 8 chunk-partials -> kvT (bf16, TRANSPOSED [e][d]) + ksum (f32)
// ---------------------------------------------------------------------------
__global__ __launch_bounds__(256) void kv_reduce(
    const float* __restrict__ kvp, const float* __restrict__ ksp,
    unsigned short* __restrict__ kvT, float* __restrict__ ksum)
{
    const int bh = blockIdx.x, t = threadIdx.x;
    const float* src = kvp + (size_t)bh * 8 * 4096;
#pragma unroll
    for (int i = 0; i < 16; ++i) {
        const int idx = i * 256 + t;
        float s = 0.f;
#pragma unroll
        for (int c = 0; c < 8; ++c) s += src[c * 4096 + idx];
        const int d = idx >> 6, e = idx & 63;
        kvT[(size_t)bh * 4096 + e * 64 + d] = f2bf(s);
    }
    if (t < 64) {
        float s = 0.f;
#pragma unroll
        for (int c = 0; c < 8; ++c) s += ksp[((size_t)bh * 8 + c) * 64 + t];
        ksum[bh * 64 + t] = s;
    }
}

// ---------------------------------------------------------------------------
// attention output: per (bh, 128-row tile): O = (q @ kv) * 1/(q.ksum+eps),
// bf16 in-place over the q columns. q@kv done as MFMA A.B^T with B=kvT[e][d].
// ---------------------------------------------------------------------------
__global__ __launch_bounds__(256) void attn_mfma(
    unsigned short* __restrict__ qkv, const unsigned short* __restrict__ kvT,
    const float* __restrict__ ksum)
{
    const int bh = blockIdx.x;   // 64
    const int mt = blockIdx.y;   // 32 tiles of 128 rows
    const int b = bh >> 3, h = bh & 7;

    __shared__ unsigned short qs[128][72];   // row stride 144B (16B aligned)
    __shared__ unsigned short kvs[64][72];
    __shared__ float dn[128];
    __shared__ float kss[64];

    const int t = threadIdx.x;
    unsigned short* qbase = qkv + ((size_t)b * Nc + (size_t)mt * 128) * QKVC + h * 64;

    // stage q tile (128 x 64 bf16)
#pragma unroll
    for (int s = 0; s < 4; ++s) {
        const int c = t + 256 * s;
        const int row = c >> 3, sl = c & 7;
        ushort8v qv = *reinterpret_cast<const ushort8v*>(qbase + (size_t)row * QKVC + sl * 8);
        *reinterpret_cast<ushort8v*>(&qs[row][sl * 8]) = qv;
    }
    // stage kvT (64 x 64 bf16)
    const unsigned short* kvbase = kvT + (size_t)bh * 4096;
#pragma unroll
    for (int s = 0; s < 2; ++s) {
        const int c = t + 256 * s;
        const int e = c >> 3, sl = c & 7;
        ushort8v v = *reinterpret_cast<const ushort8v*>(kvbase + e * 64 + sl * 8);
        *reinterpret_cast<ushort8v*>(&kvs[e][sl * 8]) = v;
    }
    if (t < 64) kss[t] = ksum[bh * 64 + t];
    __syncthreads();

    // denominators (rows 0..127)
    if (t < 128) {
        float s = EPSF;
#pragma unroll
        for (int d = 0; d < 64; ++d) s += bf2f(qs[t][d]) * kss[d];
        dn[t] = 1.0f / s;
    }
    __syncthreads();

    const int w = t >> 6, lane = t & 63;
    const int ln = lane & 15, g = lane >> 4;

    float4v acc[2][4];
#pragma unroll
    for (int i = 0; i < 2; ++i)
#pragma unroll
        for (int j = 0; j < 4; ++j) acc[i][j] = {0.f, 0.f, 0.f, 0.f};

    short8v a[2][2], bf[4][2];
#pragma unroll
    for (int i = 0; i < 2; ++i)
#pragma unroll
        for (int kk = 0; kk < 2; ++kk)
            a[i][kk] = *reinterpret_cast<const short8v*>(&qs[w * 32 + i * 16 + ln][kk * 32 + g * 8]);
#pragma unroll
    for (int j = 0; j < 4; ++j)
#pragma unroll
        for (int kk = 0; kk < 2; ++kk)
            bf[j][kk] = *reinterpret_cast<const short8v*>(&kvs[j * 16 + ln][kk * 32 + g * 8]);

#pragma unroll
    for (int kk = 0; kk < 2; ++kk)
#pragma unroll
        for (int i = 0; i < 2; ++i)
#pragma unroll
            for (int j = 0; j < 4; ++j)
                acc[i][j] = __builtin_amdgcn_mfma_f32_16x16x32_bf16(a[i][kk], bf[j][kk], acc[i][j], 0, 0, 0);

#pragma unroll
    for (int i = 0; i < 2; ++i) {
        const int lrow = w * 32 + i * 16 + g * 4;
#pragma unroll
        for (int j = 0; j < 4; ++j) {
            const int e = j * 16 + ln;
#pragma unroll
            for (int r = 0; r < 4; ++r) {
                float v = acc[i][j][r] * dn[lrow + r];
                qbase[(size_t)(lrow + r) * QKVC + e] = f2bf(v);
            }
        }
    }
}

// ---------------------------------------------------------------------------
extern "C" void kernel_launch(void* const* d_in, const int* in_sizes, int n_in,
                              void* d_out, int out_size, void* d_ws, size_t ws_size,
                              hipStream_t stream)
{
    const float* x      = (const float*)d_in[0];  // [8,4096,512]
    const float* w_qkv  = (const float*)d_in[1];  // [1536,512]
    const float* w_proj = (const float*)d_in[2];  // [512,512]
    const float* b_proj = (const float*)d_in[3];  // [512]
    float* out = (float*)d_out;

    char* ws = (char*)d_ws;
    unsigned short* qkvb = (unsigned short*)ws;                    // 96 MiB
    size_t off = (size_t)32768 * 1536 * 2;
    unsigned short* xb   = (unsigned short*)(ws + off); off += (size_t)32768 * 512 * 2;
    unsigned short* wqb  = (unsigned short*)(ws + off); off += (size_t)1536 * 512 * 2;
    unsigned short* wpb  = (unsigned short*)(ws + off); off += (size_t)512 * 512 * 2;
    float* kvp           = (float*)(ws + off);          off += (size_t)64 * 8 * 4096 * 4;
    float* ksp           = (float*)(ws + off);          off += (size_t)64 * 8 * 64 * 4;
    unsigned short* kvT  = (unsigned short*)(ws + off); off += (size_t)64 * 4096 * 2;
    float* ksumb         = (float*)(ws + off);

    // 1) convert inputs to bf16
    cvt_f32_bf16<<<dim3((32768 * 512 / 8 + 255) / 256), dim3(256), 0, stream>>>(x, xb, 32768 * 512 / 8);
    cvt_f32_bf16<<<dim3((1536 * 512 / 8 + 255) / 256), dim3(256), 0, stream>>>(w_qkv, wqb, 1536 * 512 / 8);
    cvt_f32_bf16<<<dim3((512 * 512 / 8 + 255) / 256), dim3(256), 0, stream>>>(w_proj, wpb, 512 * 512 / 8);

    // 2) qkv = elu1(x @ w_qkv^T) (elu on cols<1024), bf16 out
    gemm_bf16<1024, false, true><<<dim3(256, 12), dim3(256), 0, stream>>>(
        xb, Dc, wqb, Dc, qkvb, QKVC, Dc, nullptr);

    // 3) kv partials + reduce (-> kvT bf16 [e][d], ksum f32)
    kv_part<<<dim3(64, 8), dim3(256), 0, stream>>>(qkvb, kvp, ksp);
    kv_reduce<<<dim3(64), dim3(256), 0, stream>>>(kvp, ksp, kvT, ksumb);

    // 4) attention output, bf16 in-place over q columns
    attn_mfma<<<dim3(64, 32), dim3(256), 0, stream>>>(qkvb, kvT, ksumb);

    // 5) out = attn @ w_proj^T + b_proj (f32 out)
    gemm_bf16<0, true, false><<<dim3(256, 4), dim3(256), 0, stream>>>(
        qkvb, QKVC, wpb, Dc, out, Dc, Dc, b_proj);
}

// Round 4
// 203.038 us; speedup vs baseline: 8.4840x; 1.0661x over previous
//
#include <hip/hip_runtime.h>
#include <hip/hip_bf16.h>
#include <math.h>

#define EPSF 1e-6f

constexpr int Bc = 8;
constexpr int Nc = 4096;
constexpr int Dc = 512;
constexpr int QKVC = 3 * Dc;  // 1536

typedef __attribute__((ext_vector_type(8))) short short8v;
typedef __attribute__((ext_vector_type(8))) unsigned short ushort8v;
typedef __attribute__((ext_vector_type(4))) float float4v;

__device__ __forceinline__ unsigned short f2bf(float f) {
    union { float f; unsigned int u; } v; v.f = f;
    unsigned int u = v.u;
    return (unsigned short)((u + 0x7fffu + ((u >> 16) & 1u)) >> 16);
}
__device__ __forceinline__ float bf2f(unsigned short h) {
    union { unsigned int u; float f; } v; v.u = ((unsigned int)h) << 16;
    return v.f;
}

typedef __attribute__((address_space(1))) const void gvoid_t;
typedef __attribute__((address_space(3))) void lvoid_t;
__device__ __forceinline__ void llds16(const void* g, void* l) {
    __builtin_amdgcn_global_load_lds((gvoid_t*)g, (lvoid_t*)l, 16, 0, 0);
}

// ---------------------------------------------------------------------------
// f32 -> bf16 conversion, 8 elems/thread
// ---------------------------------------------------------------------------
__global__ __launch_bounds__(256) void cvt_f32_bf16(
    const float* __restrict__ in, unsigned short* __restrict__ out, int n8)
{
    int i = blockIdx.x * 256 + threadIdx.x;
    if (i >= n8) return;
    float4 a = reinterpret_cast<const float4*>(in)[2 * i];
    float4 b = reinterpret_cast<const float4*>(in)[2 * i + 1];
    ushort8v o;
    o[0] = f2bf(a.x); o[1] = f2bf(a.y); o[2] = f2bf(a.z); o[3] = f2bf(a.w);
    o[4] = f2bf(b.x); o[5] = f2bf(b.y); o[6] = f2bf(b.z); o[7] = f2bf(b.w);
    reinterpret_cast<ushort8v*>(out)[i] = o;
}

// ---------------------------------------------------------------------------
// bf16 MFMA GEMM: C[M,N] = A[M,K] @ Bm[N,K]^T   (both row-major, K-contig)
// 128x128 tile, BK=32, 256 threads (4 waves, 2x2), 4x4 frags of 16x16x32/wave.
// T3-minimum 2-phase: double-buffered LDS, next-tile global_load_lds issued
// BEFORE current-tile ds_read+MFMA, ONE __syncthreads (= vmcnt0+barrier) per
// K-step. T5 setprio around the MFMA cluster.
// ---------------------------------------------------------------------------
template <int ELU_COLS, bool BIAS, bool OUT_BF16>
__global__ __launch_bounds__(256) void gemm_bf16(
    const unsigned short* __restrict__ A, int lda,
    const unsigned short* __restrict__ Bm, int ldb,
    void* __restrict__ Cout, int ldc, int K,
    const float* __restrict__ bias)
{
    __shared__ unsigned short lA[2][128 * 32];
    __shared__ unsigned short lB[2][128 * 32];

    const int t    = threadIdx.x;
    const int bm   = blockIdx.x * 128;
    const int bn   = blockIdx.y * 128;
    const int w    = t >> 6, lane = t & 63;
    const int ln   = lane & 15, g = lane >> 4;
    const int wr   = (w >> 1) * 64, wc = (w & 1) * 64;

    // staging: chunk c (0..511) -> LDS ushort off c*8; row=c>>2, kslot=(c&3)*8
    const int r0  = t >> 2;
    const int ks0 = (t & 3) * 8;
    const unsigned short* Ap0 = A + (size_t)(bm + r0) * lda + ks0;
    const unsigned short* Ap1 = A + (size_t)(bm + r0 + 64) * lda + ks0;
    const unsigned short* Bp0 = Bm + (size_t)(bn + r0) * ldb + ks0;
    const unsigned short* Bp1 = Bm + (size_t)(bn + r0 + 64) * ldb + ks0;

    float4v acc[4][4];
#pragma unroll
    for (int i = 0; i < 4; ++i)
#pragma unroll
        for (int j = 0; j < 4; ++j) acc[i][j] = {0.f, 0.f, 0.f, 0.f};

    const int nt = K >> 5;

#define STAGE_T(buf, k0) do { \
        llds16(Ap0 + (k0), lA[buf] + (size_t)t * 8); \
        llds16(Ap1 + (k0), lA[buf] + (size_t)(t + 256) * 8); \
        llds16(Bp0 + (k0), lB[buf] + (size_t)t * 8); \
        llds16(Bp1 + (k0), lB[buf] + (size_t)(t + 256) * 8); \
    } while (0)

    STAGE_T(0, 0);
    __syncthreads();   // vmcnt(0) + barrier: buf0 ready

    int cur = 0;
    for (int tt = 0; tt < nt; ++tt) {
        if (tt + 1 < nt) STAGE_T(cur ^ 1, (tt + 1) << 5);   // prefetch overlaps MFMA

        const unsigned short* pa = lA[cur];
        const unsigned short* pb = lB[cur];
        short8v a[4], b[4];
#pragma unroll
        for (int i = 0; i < 4; ++i)
            a[i] = *reinterpret_cast<const short8v*>(pa + (wr + i * 16 + ln) * 32 + g * 8);
#pragma unroll
        for (int j = 0; j < 4; ++j)
            b[j] = *reinterpret_cast<const short8v*>(pb + (wc + j * 16 + ln) * 32 + g * 8);

        __builtin_amdgcn_s_setprio(1);
#pragma unroll
        for (int i = 0; i < 4; ++i)
#pragma unroll
            for (int j = 0; j < 4; ++j)
                acc[i][j] = __builtin_amdgcn_mfma_f32_16x16x32_bf16(a[i], b[j], acc[i][j], 0, 0, 0);
        __builtin_amdgcn_s_setprio(0);

        __syncthreads();   // drains prefetch (vmcnt0) + lgkm + barrier
        cur ^= 1;
    }
#undef STAGE_T

    // epilogue: D[row=(g*4+r), col=ln] per frag (m89-verified layout)
#pragma unroll
    for (int i = 0; i < 4; ++i) {
        const int Rb = bm + wr + i * 16 + g * 4;
#pragma unroll
        for (int j = 0; j < 4; ++j) {
            const int Cc = bn + wc + j * 16 + ln;
            const bool do_elu = (ELU_COLS > 0) && (Cc < ELU_COLS);
            float bv = BIAS ? bias[Cc] : 0.f;
#pragma unroll
            for (int r = 0; r < 4; ++r) {
                float v = acc[i][j][r];
                if (do_elu) v = (v > 0.f) ? (v + 1.0f + EPSF) : (expf(v) + EPSF);
                if (BIAS) v += bv;
                if (OUT_BF16)
                    ((unsigned short*)Cout)[(size_t)(Rb + r) * ldc + Cc] = f2bf(v);
                else
                    ((float*)Cout)[(size_t)(Rb + r) * ldc + Cc] = v;
            }
        }
    }
}

// ---------------------------------------------------------------------------
// kv partials: per (bh, chunk of 512 rows): kvp[d][e] = sum k[n,d]*v[n,e],
// ksp[d] = sum k[n,d].  Deterministic (fixed order), reduced in kv_reduce.
// ---------------------------------------------------------------------------
__global__ __launch_bounds__(256) void kv_part(
    const unsigned short* __restrict__ qkv,
    float* __restrict__ kvp, float* __restrict__ ksp)
{
    const int bh = blockIdx.x, chunk = blockIdx.y;
    const int b = bh >> 3, h = bh & 7;

    __shared__ float kt[64][68];
    __shared__ float vt[64][68];
    __shared__ float ksl[4][64];

    const int t  = threadIdx.x;
    const int e  = t & 63, dg = t >> 6;
    const int rr = t >> 3, slot = t & 7;

    float acc[16] = {};
    float ks = 0.f;

    const size_t base = ((size_t)b * Nc + (size_t)chunk * 512) * QKVC + h * 64;

    for (int n0 = 0; n0 < 512; n0 += 64) {
#pragma unroll
        for (int half = 0; half < 2; ++half) {
            const int row = rr + half * 32;
            const unsigned short* kr = qkv + base + (size_t)(n0 + row) * QKVC + Dc + slot * 8;
            const unsigned short* vr = kr + Dc;
            ushort8v kq = *reinterpret_cast<const ushort8v*>(kr);
            ushort8v vq = *reinterpret_cast<const ushort8v*>(vr);
            float4 k0 = make_float4(bf2f(kq[0]), bf2f(kq[1]), bf2f(kq[2]), bf2f(kq[3]));
            float4 k1 = make_float4(bf2f(kq[4]), bf2f(kq[5]), bf2f(kq[6]), bf2f(kq[7]));
            float4 v0 = make_float4(bf2f(vq[0]), bf2f(vq[1]), bf2f(vq[2]), bf2f(vq[3]));
            float4 v1 = make_float4(bf2f(vq[4]), bf2f(vq[5]), bf2f(vq[6]), bf2f(vq[7]));
            *reinterpret_cast<float4*>(&kt[row][slot * 8])     = k0;
            *reinterpret_cast<float4*>(&kt[row][slot * 8 + 4]) = k1;
            *reinterpret_cast<float4*>(&vt[row][slot * 8])     = v0;
            *reinterpret_cast<float4*>(&vt[row][slot * 8 + 4]) = v1;
        }
        __syncthreads();
#pragma unroll 2
        for (int nn = 0; nn < 64; ++nn) {
            const float vv = vt[nn][e];
            const float4 q0 = *reinterpret_cast<const float4*>(&kt[nn][dg * 16]);
            const float4 q1 = *reinterpret_cast<const float4*>(&kt[nn][dg * 16 + 4]);
            const float4 q2 = *reinterpret_cast<const float4*>(&kt[nn][dg * 16 + 8]);
            const float4 q3 = *reinterpret_cast<const float4*>(&kt[nn][dg * 16 + 12]);
            acc[0]  += q0.x * vv; acc[1]  += q0.y * vv; acc[2]  += q0.z * vv; acc[3]  += q0.w * vv;
            acc[4]  += q1.x * vv; acc[5]  += q1.y * vv; acc[6]  += q1.z * vv; acc[7]  += q1.w * vv;
            acc[8]  += q2.x * vv; acc[9]  += q2.y * vv; acc[10] += q2.z * vv; acc[11] += q2.w * vv;
            acc[12] += q3.x * vv; acc[13] += q3.y * vv; acc[14] += q3.z * vv; acc[15] += q3.w * vv;
        }
#pragma unroll
        for (int nn = 0; nn < 16; ++nn) ks += kt[dg * 16 + nn][e];
        __syncthreads();
    }

    float* kvpp = kvp + ((size_t)bh * 8 + chunk) * 4096;
#pragma unroll
    for (int i = 0; i < 16; ++i) kvpp[(dg * 16 + i) * 64 + e] = acc[i];

    ksl[dg][e] = ks;
    __syncthreads();
    if (t < 64) ksp[((size_t)bh * 8 + chunk) * 64 + t] =
        ksl[0][t] + ksl[1][t] + ksl[2][t] + ksl[3][t];
}

// ---------------------------------------------------------------------------
// reduce 8 chunk-partials -> kvT (bf16, TRANSPOSED [e][d]) + ksum (f32)
// ---------------------------------------------------------------------------
__global__ __launch_bounds__(256) void kv_reduce(
    const float* __restrict__ kvp, const float* __restrict__ ksp,
    unsigned short* __restrict__ kvT, float* __restrict__ ksum)
{
    const int bh = blockIdx.x, t = threadIdx.x;
    const float* src = kvp + (size_t)bh * 8 * 4096;
#pragma unroll
    for (int i = 0; i < 16; ++i) {
        const int idx = i * 256 + t;
        float s = 0.f;
#pragma unroll
        for (int c = 0; c < 8; ++c) s += src[c * 4096 + idx];
        const int d = idx >> 6, e = idx & 63;
        kvT[(size_t)bh * 4096 + e * 64 + d] = f2bf(s);
    }
    if (t < 64) {
        float s = 0.f;
#pragma unroll
        for (int c = 0; c < 8; ++c) s += ksp[((size_t)bh * 8 + c) * 64 + t];
        ksum[bh * 64 + t] = s;
    }
}

// ---------------------------------------------------------------------------
// attention output: per (bh, 128-row tile): O = (q @ kv) * 1/(q.ksum+eps),
// bf16 in-place over the q columns. q@kv done as MFMA A.B^T with B=kvT[e][d].
// ---------------------------------------------------------------------------
__global__ __launch_bounds__(256) void attn_mfma(
    unsigned short* __restrict__ qkv, const unsigned short* __restrict__ kvT,
    const float* __restrict__ ksum)
{
    const int bh = blockIdx.x;   // 64
    const int mt = blockIdx.y;   // 32 tiles of 128 rows
    const int b = bh >> 3, h = bh & 7;

    __shared__ unsigned short qs[128][72];   // row stride 144B (16B aligned)
    __shared__ unsigned short kvs[64][72];
    __shared__ float dn[128];
    __shared__ float kss[64];

    const int t = threadIdx.x;
    unsigned short* qbase = qkv + ((size_t)b * Nc + (size_t)mt * 128) * QKVC + h * 64;

    // stage q tile (128 x 64 bf16)
#pragma unroll
    for (int s = 0; s < 4; ++s) {
        const int c = t + 256 * s;
        const int row = c >> 3, sl = c & 7;
        ushort8v qv = *reinterpret_cast<const ushort8v*>(qbase + (size_t)row * QKVC + sl * 8);
        *reinterpret_cast<ushort8v*>(&qs[row][sl * 8]) = qv;
    }
    // stage kvT (64 x 64 bf16)
    const unsigned short* kvbase = kvT + (size_t)bh * 4096;
#pragma unroll
    for (int s = 0; s < 2; ++s) {
        const int c = t + 256 * s;
        const int e = c >> 3, sl = c & 7;
        ushort8v v = *reinterpret_cast<const ushort8v*>(kvbase + e * 64 + sl * 8);
        *reinterpret_cast<ushort8v*>(&kvs[e][sl * 8]) = v;
    }
    if (t < 64) kss[t] = ksum[bh * 64 + t];
    __syncthreads();

    // denominators (rows 0..127)
    if (t < 128) {
        float s = EPSF;
#pragma unroll
        for (int d = 0; d < 64; ++d) s += bf2f(qs[t][d]) * kss[d];
        dn[t] = 1.0f / s;
    }
    __syncthreads();

    const int w = t >> 6, lane = t & 63;
    const int ln = lane & 15, g = lane >> 4;

    float4v acc[2][4];
#pragma unroll
    for (int i = 0; i < 2; ++i)
#pragma unroll
        for (int j = 0; j < 4; ++j) acc[i][j] = {0.f, 0.f, 0.f, 0.f};

    short8v a[2][2], bf[4][2];
#pragma unroll
    for (int i = 0; i < 2; ++i)
#pragma unroll
        for (int kk = 0; kk < 2; ++kk)
            a[i][kk] = *reinterpret_cast<const short8v*>(&qs[w * 32 + i * 16 + ln][kk * 32 + g * 8]);
#pragma unroll
    for (int j = 0; j < 4; ++j)
#pragma unroll
        for (int kk = 0; kk < 2; ++kk)
            bf[j][kk] = *reinterpret_cast<const short8v*>(&kvs[j * 16 + ln][kk * 32 + g * 8]);

#pragma unroll
    for (int kk = 0; kk < 2; ++kk)
#pragma unroll
        for (int i = 0; i < 2; ++i)
#pragma unroll
            for (int j = 0; j < 4; ++j)
                acc[i][j] = __builtin_amdgcn_mfma_f32_16x16x32_bf16(a[i][kk], bf[j][kk], acc[i][j], 0, 0, 0);

#pragma unroll
    for (int i = 0; i < 2; ++i) {
        const int lrow = w * 32 + i * 16 + g * 4;
#pragma unroll
        for (int j = 0; j < 4; ++j) {
            const int e = j * 16 + ln;
#pragma unroll
            for (int r = 0; r < 4; ++r) {
                float v = acc[i][j][r] * dn[lrow + r];
                qbase[(size_t)(lrow + r) * QKVC + e] = f2bf(v);
            }
        }
    }
}

// ---------------------------------------------------------------------------
extern "C" void kernel_launch(void* const* d_in, const int* in_sizes, int n_in,
                              void* d_out, int out_size, void* d_ws, size_t ws_size,
                              hipStream_t stream)
{
    const float* x      = (const float*)d_in[0];  // [8,4096,512]
    const float* w_qkv  = (const float*)d_in[1];  // [1536,512]
    const float* w_proj = (const float*)d_in[2];  // [512,512]
    const float* b_proj = (const float*)d_in[3];  // [512]
    float* out = (float*)d_out;

    char* ws = (char*)d_ws;
    unsigned short* qkvb = (unsigned short*)ws;                    // 96 MiB
    size_t off = (size_t)32768 * 1536 * 2;
    unsigned short* xb   = (unsigned short*)(ws + off); off += (size_t)32768 * 512 * 2;
    unsigned short* wqb  = (unsigned short*)(ws + off); off += (size_t)1536 * 512 * 2;
    unsigned short* wpb  = (unsigned short*)(ws + off); off += (size_t)512 * 512 * 2;
    float* kvp           = (float*)(ws + off);          off += (size_t)64 * 8 * 4096 * 4;
    float* ksp           = (float*)(ws + off);          off += (size_t)64 * 8 * 64 * 4;
    unsigned short* kvT  = (unsigned short*)(ws + off); off += (size_t)64 * 4096 * 2;
    float* ksumb         = (float*)(ws + off);

    // 1) convert inputs to bf16
    cvt_f32_bf16<<<dim3((32768 * 512 / 8 + 255) / 256), dim3(256), 0, stream>>>(x, xb, 32768 * 512 / 8);
    cvt_f32_bf16<<<dim3((1536 * 512 / 8 + 255) / 256), dim3(256), 0, stream>>>(w_qkv, wqb, 1536 * 512 / 8);
    cvt_f32_bf16<<<dim3((512 * 512 / 8 + 255) / 256), dim3(256), 0, stream>>>(w_proj, wpb, 512 * 512 / 8);

    // 2) qkv = elu1(x @ w_qkv^T) (elu on cols<1024), bf16 out
    gemm_bf16<1024, false, true><<<dim3(256, 12), dim3(256), 0, stream>>>(
        xb, Dc, wqb, Dc, qkvb, QKVC, Dc, nullptr);

    // 3) kv partials + reduce (-> kvT bf16 [e][d], ksum f32)
    kv_part<<<dim3(64, 8), dim3(256), 0, stream>>>(qkvb, kvp, ksp);
    kv_reduce<<<dim3(64), dim3(256), 0, stream>>>(kvp, ksp, kvT, ksumb);

    // 4) attention output, bf16 in-place over q columns
    attn_mfma<<<dim3(64, 32), dim3(256), 0, stream>>>(qkvb, kvT, ksumb);

    // 5) out = attn @ w_proj^T + b_proj (f32 out)
    gemm_bf16<0, true, false><<<dim3(256, 4), dim3(256), 0, stream>>>(
        qkvb, QKVC, wpb, Dc, out, Dc, Dc, b_proj);
}